// Round 4
// baseline (846.914 us; speedup 1.0000x reference)
//
#include <hip/hip_runtime.h>

#define NN 50000
#define NE 800000
#define FIN 256
#define C 64
#define NEG_SLOPE 0.01f

__device__ __forceinline__ float leaky(float v) { return v > 0.f ? v : NEG_SLOPE * v; }

// Full-wave (64-lane) sum on the VALU pipe via DPP (no ds_bpermute).
// row_shr 1/2/4/8 -> row sums in lanes 15/31/47/63; row_bcast15/31 fold rows;
// total lands in lane 63. old=0 makes bound_ctrl semantics irrelevant.
__device__ __forceinline__ float wave_sum(float x) {
    int v = __float_as_int(x);
#define DPP_ADD(ctrl) \
    x += __int_as_float(__builtin_amdgcn_update_dpp(0, v, ctrl, 0xF, 0xF, false)); \
    v = __float_as_int(x);
    DPP_ADD(0x111)  // row_shr:1
    DPP_ADD(0x112)  // row_shr:2
    DPP_ADD(0x114)  // row_shr:4
    DPP_ADD(0x118)  // row_shr:8
    DPP_ADD(0x142)  // row_bcast:15
    DPP_ADD(0x143)  // row_bcast:31
#undef DPP_ADD
    return __int_as_float(__builtin_amdgcn_readlane(v, 63));
}

// ---------------------------------------------------------------------------
// K0: h = leaky_relu(x @ Wf + bf). No LDS: x-row operand is wave-uniform ->
// scalar loads (s_load_dwordx16); per-lane weight column chunk in VGPRs.
// Block 256 = 4 waves; wave g owns 8 nodes; lane c = output channel.
// ---------------------------------------------------------------------------
__global__ __launch_bounds__(256) void k_feat(const float* __restrict__ x,
                                              const float* __restrict__ Wf,
                                              const float* __restrict__ bf,
                                              float* __restrict__ h) {
    const int c = threadIdx.x & 63;
    const int g = __builtin_amdgcn_readfirstlane(threadIdx.x) >> 6;
    const int base = blockIdx.x * 32 + g * 8;
    float acc[8];
#pragma unroll
    for (int i = 0; i < 8; ++i) acc[i] = 0.f;

    for (int kc = 0; kc < 8; ++kc) {
        float w[32];
#pragma unroll
        for (int j = 0; j < 32; ++j) w[j] = Wf[(kc * 32 + j) * C + c];
#pragma unroll
        for (int i = 0; i < 8; ++i) {
            int n = base + i; if (n >= NN) n = NN - 1;
            const float* xr = x + (size_t)n * FIN + kc * 32;  // wave-uniform
#pragma unroll
            for (int j = 0; j < 32; ++j) acc[i] += xr[j] * w[j];
        }
    }
    const float bias = bf[c];
#pragma unroll
    for (int i = 0; i < 8; ++i) {
        const int n = base + i;
        if (n < NN) h[(size_t)n * C + c] = leaky(acc[i] + bias);
    }
}

// ---------------------------------------------------------------------------
// K1: qkvs row layout [q(64) | k/v interleaved (128): k[c]@64+2c, v[c]@65+2c
//     | skip+bias (64)]. No LDS: h-row reads are wave-uniform scalar loads;
// wave m owns matrix m; lane holds weight column w[64] in VGPRs.
// ---------------------------------------------------------------------------
__global__ __launch_bounds__(256) void k_qkvs(const float* __restrict__ h,
                                              const float* __restrict__ Wq, const float* __restrict__ bq,
                                              const float* __restrict__ Wk, const float* __restrict__ bk,
                                              const float* __restrict__ Wv, const float* __restrict__ bv,
                                              const float* __restrict__ Ws, const float* __restrict__ bs,
                                              float* __restrict__ qkvs) {
    const int lane = threadIdx.x & 63;
    const int m = __builtin_amdgcn_readfirstlane(threadIdx.x) >> 6;
    const int base = blockIdx.x * 32;
    const float* Wm = (m == 0) ? Wq : (m == 1) ? Wk : (m == 2) ? Wv : Ws;
    const float* bm = (m == 0) ? bq : (m == 1) ? bk : (m == 2) ? bv : bs;
    float w[64];
#pragma unroll
    for (int j = 0; j < 64; ++j) w[j] = Wm[j * 64 + lane];
    const float bias = bm[lane];
    // output offset within row for this matrix (k/v interleave)
    const int ooff = (m == 0) ? lane : (m == 1) ? 64 + 2 * lane
                   : (m == 2) ? 65 + 2 * lane : 192 + lane;

    for (int n0 = 0; n0 < 32; ++n0) {
        const int nn = base + n0;
        if (nn >= NN) break;
        const float* hr = h + (size_t)nn * C;  // wave-uniform -> s_load
        float s0 = 0.f, s1 = 0.f, s2 = 0.f, s3 = 0.f;
#pragma unroll
        for (int j = 0; j < 64; j += 4) {
            s0 += hr[j]     * w[j];
            s1 += hr[j + 1] * w[j + 1];
            s2 += hr[j + 2] * w[j + 2];
            s3 += hr[j + 3] * w[j + 3];
        }
        qkvs[(size_t)nn * 256 + ooff] = (s0 + s1) + (s2 + s3) + bias;
    }
}

// ---------------------------------------------------------------------------
// CSR build: histogram -> scan -> scatter of edge records (src, ea0, ea1)
// ---------------------------------------------------------------------------
__global__ __launch_bounds__(256) void k_hist(const int* __restrict__ ei,
                                              int* __restrict__ deg) {
    const int e = blockIdx.x * 256 + threadIdx.x;
    if (e >= NE) return;
    atomicAdd(&deg[ei[NE + e]], 1);
}

__global__ __launch_bounds__(1024) void k_scan(const int* __restrict__ deg,
                                               int* __restrict__ row_ptr,
                                               int* __restrict__ cursor) {
    __shared__ int part[1024];
    const int t = threadIdx.x;
    const int beg = t * 49;
    int s = 0;
    for (int j = 0; j < 49; ++j) {
        const int i = beg + j;
        if (i < NN) s += deg[i];
    }
    part[t] = s;
    __syncthreads();
    int run = 0;
    for (int j = 0; j < t; ++j) run += part[j];
    for (int j = 0; j < 49; ++j) {
        const int i = beg + j;
        if (i < NN) { row_ptr[i] = run; cursor[i] = run; run += deg[i]; }
    }
    if (t == 1023) row_ptr[NN] = run;  // == NE
}

__global__ __launch_bounds__(256) void k_csr(const int* __restrict__ ei,
                                             const float* __restrict__ eattr,
                                             int* __restrict__ cursor,
                                             float4* __restrict__ erec) {
    const int e = blockIdx.x * 256 + threadIdx.x;
    if (e >= NE) return;
    const int dst = ei[NE + e];
    const int pos = atomicAdd(&cursor[dst], 1);
    erec[pos] = make_float4(__int_as_float(ei[e]), eattr[e * 2], eattr[e * 2 + 1], 0.f);
}

// ---------------------------------------------------------------------------
// K2: fused conv. One wave per destination, flash-style online softmax.
// Wave-uniform d / edge range / erec / src pointers (scalar loads); one
// coalesced float2 gather per edge (k,v interleaved); DPP reduce (no DS pipe).
// 4-edge unroll for memory-level parallelism.
// ---------------------------------------------------------------------------
__global__ __launch_bounds__(256) void k_conv(const int* __restrict__ row_ptr,
                                              const float4* __restrict__ erec,
                                              const float* __restrict__ We,
                                              const float* __restrict__ qkvs,
                                              float* __restrict__ hout) {
    const int lane = threadIdx.x & 63;
    const int wv = __builtin_amdgcn_readfirstlane(threadIdx.x) >> 6;
    const int d = blockIdx.x * 4 + wv;
    if (d >= NN) return;
    const float we0 = We[lane], we1 = We[C + lane];
    const float* qrow = qkvs + (size_t)d * 256;
    const float q = qrow[lane];
    const int i0 = row_ptr[d], i1 = row_ptr[d + 1];

    float m = -INFINITY, l = 0.f, acc = 0.f;
    int i = i0;
    for (; i + 3 < i1; i += 4) {
        const float4 r0 = erec[i], r1 = erec[i + 1], r2 = erec[i + 2], r3 = erec[i + 3];
        const float* b0 = qkvs + (size_t)__float_as_int(r0.x) * 256;
        const float* b1 = qkvs + (size_t)__float_as_int(r1.x) * 256;
        const float* b2 = qkvs + (size_t)__float_as_int(r2.x) * 256;
        const float* b3 = qkvs + (size_t)__float_as_int(r3.x) * 256;
        const float2 kv0 = *(const float2*)(b0 + 64 + 2 * lane);
        const float2 kv1 = *(const float2*)(b1 + 64 + 2 * lane);
        const float2 kv2 = *(const float2*)(b2 + 64 + 2 * lane);
        const float2 kv3 = *(const float2*)(b3 + 64 + 2 * lane);
        const float ec0 = r0.y * we0 + r0.z * we1;
        const float ec1 = r1.y * we0 + r1.z * we1;
        const float ec2 = r2.y * we0 + r2.z * we1;
        const float ec3 = r3.y * we0 + r3.z * we1;
        const float P0 = wave_sum(q * (kv0.x + ec0)) * 0.125f;
        const float P1 = wave_sum(q * (kv1.x + ec1)) * 0.125f;
        const float P2 = wave_sum(q * (kv2.x + ec2)) * 0.125f;
        const float P3 = wave_sum(q * (kv3.x + ec3)) * 0.125f;
        const float mn = fmaxf(fmaxf(m, fmaxf(P0, P1)), fmaxf(P2, P3));
        const float s = __expf(m - mn);
        const float e0 = __expf(P0 - mn), e1 = __expf(P1 - mn);
        const float e2 = __expf(P2 - mn), e3 = __expf(P3 - mn);
        l = l * s + ((e0 + e1) + (e2 + e3));
        acc = acc * s + (kv0.y + ec0) * e0 + (kv1.y + ec1) * e1
                      + (kv2.y + ec2) * e2 + (kv3.y + ec3) * e3;
        m = mn;
    }
    for (; i < i1; ++i) {
        const float4 r0 = erec[i];
        const float* b0 = qkvs + (size_t)__float_as_int(r0.x) * 256;
        const float2 kv0 = *(const float2*)(b0 + 64 + 2 * lane);
        const float ec0 = r0.y * we0 + r0.z * we1;
        const float P0 = wave_sum(q * (kv0.x + ec0)) * 0.125f;
        const float mn = fmaxf(m, P0);
        const float s = __expf(m - mn);
        const float e0 = __expf(P0 - mn);
        l = l * s + e0;
        acc = acc * s + (kv0.y + ec0) * e0;
        m = mn;
    }
    const float res = (l > 0.f) ? acc / l : 0.f;
    hout[(size_t)d * C + lane] = leaky(res + qrow[192 + lane]);
}

extern "C" void kernel_launch(void* const* d_in, const int* in_sizes, int n_in,
                              void* d_out, int out_size, void* d_ws, size_t ws_size,
                              hipStream_t stream) {
    const float* x     = (const float*)d_in[0];
    const int*   ei    = (const int*)d_in[1];
    const float* eattr = (const float*)d_in[2];
    const float* Wf    = (const float*)d_in[3];
    const float* bf    = (const float*)d_in[4];
    const float* Wq    = (const float*)d_in[5];
    const float* bq    = (const float*)d_in[6];
    const float* Wk    = (const float*)d_in[7];
    const float* bk    = (const float*)d_in[8];
    const float* Wv    = (const float*)d_in[9];
    const float* bv    = (const float*)d_in[10];
    const float* We    = (const float*)d_in[11];
    const float* Ws    = (const float*)d_in[12];
    const float* bs    = (const float*)d_in[13];
    float* out = (float*)d_out;

    // workspace layout
    char* p = (char*)d_ws;
    float*  h       = (float*)p;  p += (size_t)NN * C * 4;        // 12.8 MB
    float*  qkvs    = (float*)p;  p += (size_t)NN * 4 * C * 4;    // 51.2 MB
    int*    deg     = (int*)p;    p += (size_t)NN * 4;
    int*    row_ptr = (int*)p;    p += (size_t)(NN + 1) * 4;
    int*    cursor  = (int*)p;    p += (size_t)NN * 4;
    float4* erec    = (float4*)p; p += (size_t)NE * 16;           // 12.8 MB

    // CSR build (per call — ws is re-poisoned before every launch)
    hipMemsetAsync(deg, 0, (size_t)NN * 4, stream);
    k_hist<<<(NE + 255) / 256, 256, 0, stream>>>(ei, deg);
    k_scan<<<1, 1024, 0, stream>>>(deg, row_ptr, cursor);
    k_csr<<<(NE + 255) / 256, 256, 0, stream>>>(ei, eattr, cursor, erec);

    const int gemm_grid = (NN + 31) / 32;
    k_feat<<<gemm_grid, 256, 0, stream>>>(x, Wf, bf, h);

    for (int layer = 0; layer < 3; ++layer) {
        k_qkvs<<<gemm_grid, 256, 0, stream>>>(
            h, Wq, bq, Wk, bk, Wv, bv, Ws, bs, qkvs);
        float* hout = (layer == 2) ? out : h;
        k_conv<<<(NN + 3) / 4, 256, 0, stream>>>(row_ptr, erec, We, qkvs, hout);
    }
}

// Round 5
// 768.641 us; speedup vs baseline: 1.1018x; 1.1018x over previous
//
#include <hip/hip_runtime.h>

#define NN 50000
#define NE 800000
#define FIN 256
#define C 64
#define NEG_SLOPE 0.01f

__device__ __forceinline__ float leaky(float v) { return v > 0.f ? v : NEG_SLOPE * v; }

// Full-wave (64-lane) sum on the VALU pipe via DPP (no ds_bpermute).
__device__ __forceinline__ float wave_sum(float x) {
    int v = __float_as_int(x);
#define DPP_ADD(ctrl) \
    x += __int_as_float(__builtin_amdgcn_update_dpp(0, v, ctrl, 0xF, 0xF, false)); \
    v = __float_as_int(x);
    DPP_ADD(0x111)  // row_shr:1
    DPP_ADD(0x112)  // row_shr:2
    DPP_ADD(0x114)  // row_shr:4
    DPP_ADD(0x118)  // row_shr:8
    DPP_ADD(0x142)  // row_bcast:15
    DPP_ADD(0x143)  // row_bcast:31
#undef DPP_ADD
    return __int_as_float(__builtin_amdgcn_readlane(v, 63));
}

// ---------------------------------------------------------------------------
// Weight transpose: Wt[m][c][k] = W_m[k][c], m in {q,k,v,skip}. 16384 elems.
// ---------------------------------------------------------------------------
__global__ __launch_bounds__(256) void k_tw(const float* __restrict__ Wq,
                                            const float* __restrict__ Wk,
                                            const float* __restrict__ Wv,
                                            const float* __restrict__ Ws,
                                            float* __restrict__ Wt) {
    const int idx = blockIdx.x * 256 + threadIdx.x;
    if (idx >= 4 * 64 * 64) return;
    const int m = idx >> 12, r = idx & 4095, c = r >> 6, k = r & 63;
    const float* W = (m == 0) ? Wq : (m == 1) ? Wk : (m == 2) ? Wv : Ws;
    Wt[idx] = W[k * 64 + c];
}

// ---------------------------------------------------------------------------
// K0: h = leaky_relu(x @ Wf + bf).  Lane = node (64 nodes/block), activations
// register-resident via swizzled LDS transpose; weights streamed as uniform
// float4 loads (1 load : 4 wave-FMAs). Wave q computes channel quarter q.
// ---------------------------------------------------------------------------
__global__ __launch_bounds__(256) void k_feat(const float* __restrict__ x,
                                              const float* __restrict__ Wf,
                                              const float* __restrict__ bf,
                                              float* __restrict__ h) {
    __shared__ float4 T[64][64];  // T[row][col4 ^ (row&7)], 64 KB
    const int t = threadIdx.x;
    const int base = blockIdx.x * 64;
    const float4* x4 = (const float4*)x;
#pragma unroll
    for (int i = 0; i < 16; ++i) {
        const int idx = t + i * 256;        // 0..4095
        const int row = idx >> 6, c4 = idx & 63;
        int n = base + row; if (n >= NN) n = NN - 1;
        T[row][c4 ^ (row & 7)] = x4[(size_t)n * 64 + c4];
    }
    __syncthreads();
    const int lane = t & 63;
    const int q = __builtin_amdgcn_readfirstlane(t) >> 6;  // channel quarter
    const float4* Wf4 = (const float4*)Wf;                 // [k][16 float4]

    float4 acc[4];
#pragma unroll
    for (int cp = 0; cp < 4; ++cp) acc[cp] = make_float4(0.f, 0.f, 0.f, 0.f);

    for (int ch = 0; ch < 64; ++ch) {       // k-chunk of 4
        const float4 xv = T[lane][ch ^ (lane & 7)];
#pragma unroll
        for (int j = 0; j < 4; ++j) {
            const float xs_ = (j == 0) ? xv.x : (j == 1) ? xv.y : (j == 2) ? xv.z : xv.w;
            const float4* wr = Wf4 + (size_t)(4 * ch + j) * 16 + q * 4;
#pragma unroll
            for (int cp = 0; cp < 4; ++cp) {
                const float4 w = wr[cp];    // uniform address -> broadcast/SMEM
                acc[cp].x += xs_ * w.x; acc[cp].y += xs_ * w.y;
                acc[cp].z += xs_ * w.z; acc[cp].w += xs_ * w.w;
            }
        }
    }
    const int n = base + lane;
    if (n < NN) {
        const float4* bf4 = (const float4*)bf;
#pragma unroll
        for (int cp = 0; cp < 4; ++cp) {
            const float4 b = bf4[q * 4 + cp];
            float4 r;
            r.x = leaky(acc[cp].x + b.x); r.y = leaky(acc[cp].y + b.y);
            r.z = leaky(acc[cp].z + b.z); r.w = leaky(acc[cp].w + b.w);
            ((float4*)h)[(size_t)n * 16 + q * 4 + cp] = r;
        }
    }
}

// ---------------------------------------------------------------------------
// K1: qkvs row = [q(64) | k/v interleaved(128) | skip+bias(64)].
// Lane = node (64/block); h-row in 64 VGPRs (swizzled LDS fill); weights from
// transposed Wt via uniform float4 loads. Wave sections: 0=q, 1=skip,
// 2=kv c0..31, 3=kv c32..63 (k,v computed together -> float2 store).
// ---------------------------------------------------------------------------
__global__ __launch_bounds__(256) void k_qkvs(const float* __restrict__ h,
                                              const float* __restrict__ Wt,
                                              const float* __restrict__ bq,
                                              const float* __restrict__ bk,
                                              const float* __restrict__ bv,
                                              const float* __restrict__ bs,
                                              float* __restrict__ qkvs) {
    __shared__ float4 T[64][16];  // 16 KB, swizzled
    const int t = threadIdx.x;
    const int base = blockIdx.x * 64;
    const float4* h4 = (const float4*)h;
#pragma unroll
    for (int i = 0; i < 4; ++i) {
        const int idx = t + i * 256;        // 0..1023
        const int row = idx >> 4, c4 = idx & 15;
        int n = base + row; if (n >= NN) n = NN - 1;
        T[row][c4 ^ (row & 7)] = h4[(size_t)n * 16 + c4];
    }
    __syncthreads();
    const int lane = t & 63;
    const int sec = __builtin_amdgcn_readfirstlane(t) >> 6;
    const int n = base + lane;
    const bool ok = (n < NN);
    float* orow = qkvs + (size_t)n * 256;

    float4 hr[16];
#pragma unroll
    for (int j = 0; j < 16; ++j) hr[j] = T[lane][j ^ (lane & 7)];

    const float4* Wt4 = (const float4*)Wt;  // [m][c][16 float4]

#define DOT(WROW, OUT) do {                                            \
        float s0 = 0.f, s1 = 0.f, s2 = 0.f, s3 = 0.f;                  \
        _Pragma("unroll")                                              \
        for (int j = 0; j < 16; ++j) {                                 \
            const float4 w = (WROW)[j];                                \
            s0 += hr[j].x * w.x; s1 += hr[j].y * w.y;                  \
            s2 += hr[j].z * w.z; s3 += hr[j].w * w.w;                  \
        }                                                              \
        OUT = (s0 + s1) + (s2 + s3);                                   \
    } while (0)

    if (sec == 0) {               // q -> offsets [0..63]
        for (int cg = 0; cg < 16; ++cg) {
            float4 r;
            float v0, v1, v2, v3;
            DOT(Wt4 + (size_t)(4 * cg + 0) * 16, v0);
            DOT(Wt4 + (size_t)(4 * cg + 1) * 16, v1);
            DOT(Wt4 + (size_t)(4 * cg + 2) * 16, v2);
            DOT(Wt4 + (size_t)(4 * cg + 3) * 16, v3);
            const float4 b = ((const float4*)bq)[cg];
            r.x = v0 + b.x; r.y = v1 + b.y; r.z = v2 + b.z; r.w = v3 + b.w;
            if (ok) *(float4*)(orow + 4 * cg) = r;
        }
    } else if (sec == 1) {        // skip -> offsets [192..255]
        const float4* Wm = Wt4 + (size_t)3 * 64 * 16;
        for (int cg = 0; cg < 16; ++cg) {
            float4 r;
            float v0, v1, v2, v3;
            DOT(Wm + (size_t)(4 * cg + 0) * 16, v0);
            DOT(Wm + (size_t)(4 * cg + 1) * 16, v1);
            DOT(Wm + (size_t)(4 * cg + 2) * 16, v2);
            DOT(Wm + (size_t)(4 * cg + 3) * 16, v3);
            const float4 b = ((const float4*)bs)[cg];
            r.x = v0 + b.x; r.y = v1 + b.y; r.z = v2 + b.z; r.w = v3 + b.w;
            if (ok) *(float4*)(orow + 192 + 4 * cg) = r;
        }
    } else {                      // kv pairs -> offsets 64+2c (k), 65+2c (v)
        const int c0 = (sec - 2) * 32;
        const float4* Wk_ = Wt4 + (size_t)1 * 64 * 16;
        const float4* Wv_ = Wt4 + (size_t)2 * 64 * 16;
        for (int ci = 0; ci < 32; ++ci) {
            const int c = c0 + ci;
            float kc, vc;
            DOT(Wk_ + (size_t)c * 16, kc);
            DOT(Wv_ + (size_t)c * 16, vc);
            float2 r;
            r.x = kc + bk[c];
            r.y = vc + bv[c];
            if (ok) *(float2*)(orow + 64 + 2 * c) = r;
        }
    }
#undef DOT
}

// ---------------------------------------------------------------------------
// CSR build: histogram -> scan -> scatter of edge records (src, ea0, ea1)
// ---------------------------------------------------------------------------
__global__ __launch_bounds__(256) void k_hist(const int* __restrict__ ei,
                                              int* __restrict__ deg) {
    const int e = blockIdx.x * 256 + threadIdx.x;
    if (e >= NE) return;
    atomicAdd(&deg[ei[NE + e]], 1);
}

__global__ __launch_bounds__(1024) void k_scan(const int* __restrict__ deg,
                                               int* __restrict__ row_ptr,
                                               int* __restrict__ cursor) {
    __shared__ int part[1024];
    const int t = threadIdx.x;
    const int beg = t * 49;
    int s = 0;
    for (int j = 0; j < 49; ++j) {
        const int i = beg + j;
        if (i < NN) s += deg[i];
    }
    part[t] = s;
    __syncthreads();
    int run = 0;
    for (int j = 0; j < t; ++j) run += part[j];
    for (int j = 0; j < 49; ++j) {
        const int i = beg + j;
        if (i < NN) { row_ptr[i] = run; cursor[i] = run; run += deg[i]; }
    }
    if (t == 1023) row_ptr[NN] = run;  // == NE
}

__global__ __launch_bounds__(256) void k_csr(const int* __restrict__ ei,
                                             const float* __restrict__ eattr,
                                             int* __restrict__ cursor,
                                             float4* __restrict__ erec) {
    const int e = blockIdx.x * 256 + threadIdx.x;
    if (e >= NE) return;
    const int dst = ei[NE + e];
    const int pos = atomicAdd(&cursor[dst], 1);
    erec[pos] = make_float4(__int_as_float(ei[e]), eattr[e * 2], eattr[e * 2 + 1], 0.f);
}

// ---------------------------------------------------------------------------
// K2: fused conv. One wave per destination, flash-style online softmax,
// DPP reduce, float2 k/v gather, 4-edge unroll.
// ---------------------------------------------------------------------------
__global__ __launch_bounds__(256) void k_conv(const int* __restrict__ row_ptr,
                                              const float4* __restrict__ erec,
                                              const float* __restrict__ We,
                                              const float* __restrict__ qkvs,
                                              float* __restrict__ hout) {
    const int lane = threadIdx.x & 63;
    const int wv = __builtin_amdgcn_readfirstlane(threadIdx.x) >> 6;
    const int d = blockIdx.x * 4 + wv;
    if (d >= NN) return;
    const float we0 = We[lane], we1 = We[C + lane];
    const float* qrow = qkvs + (size_t)d * 256;
    const float q = qrow[lane];
    const int i0 = row_ptr[d], i1 = row_ptr[d + 1];

    float m = -INFINITY, l = 0.f, acc = 0.f;
    int i = i0;
    for (; i + 3 < i1; i += 4) {
        const float4 r0 = erec[i], r1 = erec[i + 1], r2 = erec[i + 2], r3 = erec[i + 3];
        const float* b0 = qkvs + (size_t)__float_as_int(r0.x) * 256;
        const float* b1 = qkvs + (size_t)__float_as_int(r1.x) * 256;
        const float* b2 = qkvs + (size_t)__float_as_int(r2.x) * 256;
        const float* b3 = qkvs + (size_t)__float_as_int(r3.x) * 256;
        const float2 kv0 = *(const float2*)(b0 + 64 + 2 * lane);
        const float2 kv1 = *(const float2*)(b1 + 64 + 2 * lane);
        const float2 kv2 = *(const float2*)(b2 + 64 + 2 * lane);
        const float2 kv3 = *(const float2*)(b3 + 64 + 2 * lane);
        const float ec0 = r0.y * we0 + r0.z * we1;
        const float ec1 = r1.y * we0 + r1.z * we1;
        const float ec2 = r2.y * we0 + r2.z * we1;
        const float ec3 = r3.y * we0 + r3.z * we1;
        const float P0 = wave_sum(q * (kv0.x + ec0)) * 0.125f;
        const float P1 = wave_sum(q * (kv1.x + ec1)) * 0.125f;
        const float P2 = wave_sum(q * (kv2.x + ec2)) * 0.125f;
        const float P3 = wave_sum(q * (kv3.x + ec3)) * 0.125f;
        const float mn = fmaxf(fmaxf(m, fmaxf(P0, P1)), fmaxf(P2, P3));
        const float s = __expf(m - mn);
        const float e0 = __expf(P0 - mn), e1 = __expf(P1 - mn);
        const float e2 = __expf(P2 - mn), e3 = __expf(P3 - mn);
        l = l * s + ((e0 + e1) + (e2 + e3));
        acc = acc * s + (kv0.y + ec0) * e0 + (kv1.y + ec1) * e1
                      + (kv2.y + ec2) * e2 + (kv3.y + ec3) * e3;
        m = mn;
    }
    for (; i < i1; ++i) {
        const float4 r0 = erec[i];
        const float* b0 = qkvs + (size_t)__float_as_int(r0.x) * 256;
        const float2 kv0 = *(const float2*)(b0 + 64 + 2 * lane);
        const float ec0 = r0.y * we0 + r0.z * we1;
        const float P0 = wave_sum(q * (kv0.x + ec0)) * 0.125f;
        const float mn = fmaxf(m, P0);
        const float s = __expf(m - mn);
        const float e0 = __expf(P0 - mn);
        l = l * s + e0;
        acc = acc * s + (kv0.y + ec0) * e0;
        m = mn;
    }
    const float res = (l > 0.f) ? acc / l : 0.f;
    hout[(size_t)d * C + lane] = leaky(res + qrow[192 + lane]);
}

extern "C" void kernel_launch(void* const* d_in, const int* in_sizes, int n_in,
                              void* d_out, int out_size, void* d_ws, size_t ws_size,
                              hipStream_t stream) {
    const float* x     = (const float*)d_in[0];
    const int*   ei    = (const int*)d_in[1];
    const float* eattr = (const float*)d_in[2];
    const float* Wf    = (const float*)d_in[3];
    const float* bf    = (const float*)d_in[4];
    const float* Wq    = (const float*)d_in[5];
    const float* bq    = (const float*)d_in[6];
    const float* Wk    = (const float*)d_in[7];
    const float* bk    = (const float*)d_in[8];
    const float* Wv    = (const float*)d_in[9];
    const float* bv    = (const float*)d_in[10];
    const float* We    = (const float*)d_in[11];
    const float* Ws    = (const float*)d_in[12];
    const float* bs    = (const float*)d_in[13];
    float* out = (float*)d_out;

    // workspace layout
    char* p = (char*)d_ws;
    float*  h       = (float*)p;  p += (size_t)NN * C * 4;        // 12.8 MB
    float*  qkvs    = (float*)p;  p += (size_t)NN * 4 * C * 4;    // 51.2 MB
    float*  Wt      = (float*)p;  p += (size_t)4 * 64 * 64 * 4;   // 64 KB
    int*    deg     = (int*)p;    p += (size_t)NN * 4;
    int*    row_ptr = (int*)p;    p += (size_t)(NN + 1) * 4;
    int*    cursor  = (int*)p;    p += (size_t)NN * 4;
    float4* erec    = (float4*)p; p += (size_t)NE * 16;           // 12.8 MB

    // One-time per call: weight transpose + CSR build
    k_tw<<<64, 256, 0, stream>>>(Wq, Wk, Wv, Ws, Wt);
    hipMemsetAsync(deg, 0, (size_t)NN * 4, stream);
    k_hist<<<(NE + 255) / 256, 256, 0, stream>>>(ei, deg);
    k_scan<<<1, 1024, 0, stream>>>(deg, row_ptr, cursor);
    k_csr<<<(NE + 255) / 256, 256, 0, stream>>>(ei, eattr, cursor, erec);

    const int gemm_grid = (NN + 63) / 64;   // 782
    k_feat<<<gemm_grid, 256, 0, stream>>>(x, Wf, bf, h);

    for (int layer = 0; layer < 3; ++layer) {
        k_qkvs<<<gemm_grid, 256, 0, stream>>>(h, Wt, bq, bk, bv, bs, qkvs);
        float* hout = (layer == 2) ? out : h;
        k_conv<<<(NN + 3) / 4, 256, 0, stream>>>(row_ptr, erec, We, qkvs, hout);
    }
}

// Round 6
// 645.214 us; speedup vs baseline: 1.3126x; 1.1913x over previous
//
#include <hip/hip_runtime.h>

#define NN 50000
#define NE 800000
#define FIN 256
#define C 64
#define NEG_SLOPE 0.01f
#define SCAN_BLOCKS ((NN + 255) / 256)   // 196

__device__ __forceinline__ float leaky(float v) { return v > 0.f ? v : NEG_SLOPE * v; }

// Full-wave (64-lane) sum on the VALU pipe via DPP (no ds_bpermute).
__device__ __forceinline__ float wave_sum(float x) {
    int v = __float_as_int(x);
#define DPP_ADD(ctrl) \
    x += __int_as_float(__builtin_amdgcn_update_dpp(0, v, ctrl, 0xF, 0xF, false)); \
    v = __float_as_int(x);
    DPP_ADD(0x111)  // row_shr:1
    DPP_ADD(0x112)  // row_shr:2
    DPP_ADD(0x114)  // row_shr:4
    DPP_ADD(0x118)  // row_shr:8
    DPP_ADD(0x142)  // row_bcast:15
    DPP_ADD(0x143)  // row_bcast:31
#undef DPP_ADD
    return __int_as_float(__builtin_amdgcn_readlane(v, 63));
}

// ---------------------------------------------------------------------------
// Weight transpose: Wt[m][c][k] = W_m[k][c], m in {q,k,v,skip}. 16384 elems.
// ---------------------------------------------------------------------------
__global__ __launch_bounds__(256) void k_tw(const float* __restrict__ Wq,
                                            const float* __restrict__ Wk,
                                            const float* __restrict__ Wv,
                                            const float* __restrict__ Ws,
                                            float* __restrict__ Wt) {
    const int idx = blockIdx.x * 256 + threadIdx.x;
    if (idx >= 4 * 64 * 64) return;
    const int m = idx >> 12, r = idx & 4095, c = r >> 6, k = r & 63;
    const float* W = (m == 0) ? Wq : (m == 1) ? Wk : (m == 2) ? Wv : Ws;
    Wt[idx] = W[k * 64 + c];
}

// ---------------------------------------------------------------------------
// K0: h = leaky_relu(x @ Wf + bf).  Lane = node; weights streamed uniform.
// ---------------------------------------------------------------------------
__global__ __launch_bounds__(256) void k_feat(const float* __restrict__ x,
                                              const float* __restrict__ Wf,
                                              const float* __restrict__ bf,
                                              float* __restrict__ h) {
    __shared__ float4 T[64][64];  // swizzled, 64 KB
    const int t = threadIdx.x;
    const int base = blockIdx.x * 64;
    const float4* x4 = (const float4*)x;
#pragma unroll
    for (int i = 0; i < 16; ++i) {
        const int idx = t + i * 256;
        const int row = idx >> 6, c4 = idx & 63;
        int n = base + row; if (n >= NN) n = NN - 1;
        T[row][c4 ^ (row & 7)] = x4[(size_t)n * 64 + c4];
    }
    __syncthreads();
    const int lane = t & 63;
    const int q = __builtin_amdgcn_readfirstlane(t) >> 6;
    const float4* Wf4 = (const float4*)Wf;

    float4 acc[4];
#pragma unroll
    for (int cp = 0; cp < 4; ++cp) acc[cp] = make_float4(0.f, 0.f, 0.f, 0.f);

    for (int ch = 0; ch < 64; ++ch) {
        const float4 xv = T[lane][ch ^ (lane & 7)];
#pragma unroll
        for (int j = 0; j < 4; ++j) {
            const float xs_ = (j == 0) ? xv.x : (j == 1) ? xv.y : (j == 2) ? xv.z : xv.w;
            const float4* wr = Wf4 + (size_t)(4 * ch + j) * 16 + q * 4;
#pragma unroll
            for (int cp = 0; cp < 4; ++cp) {
                const float4 w = wr[cp];
                acc[cp].x += xs_ * w.x; acc[cp].y += xs_ * w.y;
                acc[cp].z += xs_ * w.z; acc[cp].w += xs_ * w.w;
            }
        }
    }
    const int n = base + lane;
    if (n < NN) {
        const float4* bf4 = (const float4*)bf;
#pragma unroll
        for (int cp = 0; cp < 4; ++cp) {
            const float4 b = bf4[q * 4 + cp];
            float4 r;
            r.x = leaky(acc[cp].x + b.x); r.y = leaky(acc[cp].y + b.y);
            r.z = leaky(acc[cp].z + b.z); r.w = leaky(acc[cp].w + b.w);
            ((float4*)h)[(size_t)n * 16 + q * 4 + cp] = r;
        }
    }
}

// ---------------------------------------------------------------------------
// K1: qkvs row = [q(64) | k/v interleaved(128) | skip+bias(64)].
// ---------------------------------------------------------------------------
__global__ __launch_bounds__(256) void k_qkvs(const float* __restrict__ h,
                                              const float* __restrict__ Wt,
                                              const float* __restrict__ bq,
                                              const float* __restrict__ bk,
                                              const float* __restrict__ bv,
                                              const float* __restrict__ bs,
                                              float* __restrict__ qkvs) {
    __shared__ float4 T[64][16];
    const int t = threadIdx.x;
    const int base = blockIdx.x * 64;
    const float4* h4 = (const float4*)h;
#pragma unroll
    for (int i = 0; i < 4; ++i) {
        const int idx = t + i * 256;
        const int row = idx >> 4, c4 = idx & 15;
        int n = base + row; if (n >= NN) n = NN - 1;
        T[row][c4 ^ (row & 7)] = h4[(size_t)n * 16 + c4];
    }
    __syncthreads();
    const int lane = t & 63;
    const int sec = __builtin_amdgcn_readfirstlane(t) >> 6;
    const int n = base + lane;
    const bool ok = (n < NN);
    float* orow = qkvs + (size_t)n * 256;

    float4 hr[16];
#pragma unroll
    for (int j = 0; j < 16; ++j) hr[j] = T[lane][j ^ (lane & 7)];

    const float4* Wt4 = (const float4*)Wt;

#define DOT(WROW, OUT) do {                                            \
        float s0 = 0.f, s1 = 0.f, s2 = 0.f, s3 = 0.f;                  \
        _Pragma("unroll")                                              \
        for (int j = 0; j < 16; ++j) {                                 \
            const float4 w = (WROW)[j];                                \
            s0 += hr[j].x * w.x; s1 += hr[j].y * w.y;                  \
            s2 += hr[j].z * w.z; s3 += hr[j].w * w.w;                  \
        }                                                              \
        OUT = (s0 + s1) + (s2 + s3);                                   \
    } while (0)

    if (sec == 0) {               // q
        for (int cg = 0; cg < 16; ++cg) {
            float v0, v1, v2, v3;
            DOT(Wt4 + (size_t)(4 * cg + 0) * 16, v0);
            DOT(Wt4 + (size_t)(4 * cg + 1) * 16, v1);
            DOT(Wt4 + (size_t)(4 * cg + 2) * 16, v2);
            DOT(Wt4 + (size_t)(4 * cg + 3) * 16, v3);
            const float4 b = ((const float4*)bq)[cg];
            float4 r;
            r.x = v0 + b.x; r.y = v1 + b.y; r.z = v2 + b.z; r.w = v3 + b.w;
            if (ok) *(float4*)(orow + 4 * cg) = r;
        }
    } else if (sec == 1) {        // skip
        const float4* Wm = Wt4 + (size_t)3 * 64 * 16;
        for (int cg = 0; cg < 16; ++cg) {
            float v0, v1, v2, v3;
            DOT(Wm + (size_t)(4 * cg + 0) * 16, v0);
            DOT(Wm + (size_t)(4 * cg + 1) * 16, v1);
            DOT(Wm + (size_t)(4 * cg + 2) * 16, v2);
            DOT(Wm + (size_t)(4 * cg + 3) * 16, v3);
            const float4 b = ((const float4*)bs)[cg];
            float4 r;
            r.x = v0 + b.x; r.y = v1 + b.y; r.z = v2 + b.z; r.w = v3 + b.w;
            if (ok) *(float4*)(orow + 192 + 4 * cg) = r;
        }
    } else {                      // kv pairs
        const int c0 = (sec - 2) * 32;
        const float4* Wk_ = Wt4 + (size_t)1 * 64 * 16;
        const float4* Wv_ = Wt4 + (size_t)2 * 64 * 16;
        for (int ci = 0; ci < 32; ++ci) {
            const int c = c0 + ci;
            float kc, vc;
            DOT(Wk_ + (size_t)c * 16, kc);
            DOT(Wv_ + (size_t)c * 16, vc);
            float2 r;
            r.x = kc + bk[c];
            r.y = vc + bv[c];
            if (ok) *(float2*)(orow + 64 + 2 * c) = r;
        }
    }
#undef DOT
}

// ---------------------------------------------------------------------------
// CSR build: histogram -> 3-kernel parallel scan -> scatter
// ---------------------------------------------------------------------------
__global__ __launch_bounds__(256) void k_hist(const int* __restrict__ ei,
                                              int* __restrict__ deg) {
    const int e = blockIdx.x * 256 + threadIdx.x;
    if (e >= NE) return;
    atomicAdd(&deg[ei[NE + e]], 1);
}

__global__ __launch_bounds__(256) void k_blocksum(const int* __restrict__ deg,
                                                  int* __restrict__ bsum) {
    __shared__ int sh[256];
    const int t = threadIdx.x;
    const int idx = blockIdx.x * 256 + t;
    sh[t] = (idx < NN) ? deg[idx] : 0;
    __syncthreads();
#pragma unroll
    for (int off = 128; off > 0; off >>= 1) {
        if (t < off) sh[t] += sh[t + off];
        __syncthreads();
    }
    if (t == 0) bsum[blockIdx.x] = sh[0];
}

__global__ __launch_bounds__(256) void k_scanb(const int* __restrict__ bsum,
                                               int* __restrict__ boff) {
    __shared__ int sh[256];
    const int t = threadIdx.x;
    const int v = (t < SCAN_BLOCKS) ? bsum[t] : 0;
    sh[t] = v;
    __syncthreads();
#pragma unroll
    for (int off = 1; off < 256; off <<= 1) {
        const int x = (t >= off) ? sh[t - off] : 0;
        __syncthreads();
        sh[t] += x;
        __syncthreads();
    }
    if (t < SCAN_BLOCKS) boff[t] = sh[t] - v;  // exclusive
}

__global__ __launch_bounds__(256) void k_writeptr(const int* __restrict__ deg,
                                                  const int* __restrict__ boff,
                                                  int* __restrict__ row_ptr,
                                                  int* __restrict__ cursor) {
    __shared__ int sh[256];
    const int t = threadIdx.x;
    const int idx = blockIdx.x * 256 + t;
    const int v = (idx < NN) ? deg[idx] : 0;
    sh[t] = v;
    __syncthreads();
#pragma unroll
    for (int off = 1; off < 256; off <<= 1) {
        const int x = (t >= off) ? sh[t - off] : 0;
        __syncthreads();
        sh[t] += x;
        __syncthreads();
    }
    if (idx < NN) {
        const int r = boff[blockIdx.x] + sh[t] - v;  // exclusive prefix
        row_ptr[idx] = r;
        cursor[idx] = r;
    }
    if (idx == 0) row_ptr[NN] = NE;
}

__global__ __launch_bounds__(256) void k_csr(const int* __restrict__ ei,
                                             const float* __restrict__ eattr,
                                             int* __restrict__ cursor,
                                             float4* __restrict__ erec) {
    const int e = blockIdx.x * 256 + threadIdx.x;
    if (e >= NE) return;
    const int dst = ei[NE + e];
    const int pos = atomicAdd(&cursor[dst], 1);
    erec[pos] = make_float4(__int_as_float(ei[e]), eattr[e * 2], eattr[e * 2 + 1], 0.f);
}

// ---------------------------------------------------------------------------
// K2: fused conv. One wave per destination, flash-style online softmax,
// DPP reduce, float2 k/v gather, 4-edge unroll.
// ---------------------------------------------------------------------------
__global__ __launch_bounds__(256) void k_conv(const int* __restrict__ row_ptr,
                                              const float4* __restrict__ erec,
                                              const float* __restrict__ We,
                                              const float* __restrict__ qkvs,
                                              float* __restrict__ hout) {
    const int lane = threadIdx.x & 63;
    const int wv = __builtin_amdgcn_readfirstlane(threadIdx.x) >> 6;
    const int d = blockIdx.x * 4 + wv;
    if (d >= NN) return;
    const float we0 = We[lane], we1 = We[C + lane];
    const float* qrow = qkvs + (size_t)d * 256;
    const float q = qrow[lane];
    const int i0 = row_ptr[d], i1 = row_ptr[d + 1];

    float m = -INFINITY, l = 0.f, acc = 0.f;
    int i = i0;
    for (; i + 3 < i1; i += 4) {
        const float4 r0 = erec[i], r1 = erec[i + 1], r2 = erec[i + 2], r3 = erec[i + 3];
        const float* b0 = qkvs + (size_t)__float_as_int(r0.x) * 256;
        const float* b1 = qkvs + (size_t)__float_as_int(r1.x) * 256;
        const float* b2 = qkvs + (size_t)__float_as_int(r2.x) * 256;
        const float* b3 = qkvs + (size_t)__float_as_int(r3.x) * 256;
        const float2 kv0 = *(const float2*)(b0 + 64 + 2 * lane);
        const float2 kv1 = *(const float2*)(b1 + 64 + 2 * lane);
        const float2 kv2 = *(const float2*)(b2 + 64 + 2 * lane);
        const float2 kv3 = *(const float2*)(b3 + 64 + 2 * lane);
        const float ec0 = r0.y * we0 + r0.z * we1;
        const float ec1 = r1.y * we0 + r1.z * we1;
        const float ec2 = r2.y * we0 + r2.z * we1;
        const float ec3 = r3.y * we0 + r3.z * we1;
        const float P0 = wave_sum(q * (kv0.x + ec0)) * 0.125f;
        const float P1 = wave_sum(q * (kv1.x + ec1)) * 0.125f;
        const float P2 = wave_sum(q * (kv2.x + ec2)) * 0.125f;
        const float P3 = wave_sum(q * (kv3.x + ec3)) * 0.125f;
        const float mn = fmaxf(fmaxf(m, fmaxf(P0, P1)), fmaxf(P2, P3));
        const float s = __expf(m - mn);
        const float e0 = __expf(P0 - mn), e1 = __expf(P1 - mn);
        const float e2 = __expf(P2 - mn), e3 = __expf(P3 - mn);
        l = l * s + ((e0 + e1) + (e2 + e3));
        acc = acc * s + (kv0.y + ec0) * e0 + (kv1.y + ec1) * e1
                      + (kv2.y + ec2) * e2 + (kv3.y + ec3) * e3;
        m = mn;
    }
    for (; i < i1; ++i) {
        const float4 r0 = erec[i];
        const float* b0 = qkvs + (size_t)__float_as_int(r0.x) * 256;
        const float2 kv0 = *(const float2*)(b0 + 64 + 2 * lane);
        const float ec0 = r0.y * we0 + r0.z * we1;
        const float P0 = wave_sum(q * (kv0.x + ec0)) * 0.125f;
        const float mn = fmaxf(m, P0);
        const float s = __expf(m - mn);
        const float e0 = __expf(P0 - mn);
        l = l * s + e0;
        acc = acc * s + (kv0.y + ec0) * e0;
        m = mn;
    }
    const float res = (l > 0.f) ? acc / l : 0.f;
    hout[(size_t)d * C + lane] = leaky(res + qrow[192 + lane]);
}

extern "C" void kernel_launch(void* const* d_in, const int* in_sizes, int n_in,
                              void* d_out, int out_size, void* d_ws, size_t ws_size,
                              hipStream_t stream) {
    const float* x     = (const float*)d_in[0];
    const int*   ei    = (const int*)d_in[1];
    const float* eattr = (const float*)d_in[2];
    const float* Wf    = (const float*)d_in[3];
    const float* bf    = (const float*)d_in[4];
    const float* Wq    = (const float*)d_in[5];
    const float* bq    = (const float*)d_in[6];
    const float* Wk    = (const float*)d_in[7];
    const float* bk    = (const float*)d_in[8];
    const float* Wv    = (const float*)d_in[9];
    const float* bv    = (const float*)d_in[10];
    const float* We    = (const float*)d_in[11];
    const float* Ws    = (const float*)d_in[12];
    const float* bs    = (const float*)d_in[13];
    float* out = (float*)d_out;

    // workspace layout
    char* p = (char*)d_ws;
    float*  h       = (float*)p;  p += (size_t)NN * C * 4;        // 12.8 MB
    float*  qkvs    = (float*)p;  p += (size_t)NN * 4 * C * 4;    // 51.2 MB
    float*  Wt      = (float*)p;  p += (size_t)4 * 64 * 64 * 4;   // 64 KB
    int*    deg     = (int*)p;    p += (size_t)NN * 4;
    int*    row_ptr = (int*)p;    p += (size_t)(NN + 1) * 4;
    int*    cursor  = (int*)p;    p += (size_t)NN * 4;
    int*    bsum    = (int*)p;    p += (size_t)SCAN_BLOCKS * 4;
    int*    boff    = (int*)p;    p += (size_t)SCAN_BLOCKS * 4;
    float4* erec    = (float4*)p; p += (size_t)NE * 16;           // 12.8 MB

    // One-time per call: weight transpose + CSR build
    k_tw<<<64, 256, 0, stream>>>(Wq, Wk, Wv, Ws, Wt);
    hipMemsetAsync(deg, 0, (size_t)NN * 4, stream);
    k_hist<<<(NE + 255) / 256, 256, 0, stream>>>(ei, deg);
    k_blocksum<<<SCAN_BLOCKS, 256, 0, stream>>>(deg, bsum);
    k_scanb<<<1, 256, 0, stream>>>(bsum, boff);
    k_writeptr<<<SCAN_BLOCKS, 256, 0, stream>>>(deg, boff, row_ptr, cursor);
    k_csr<<<(NE + 255) / 256, 256, 0, stream>>>(ei, eattr, cursor, erec);

    const int gemm_grid = (NN + 63) / 64;   // 782
    k_feat<<<gemm_grid, 256, 0, stream>>>(x, Wf, bf, h);

    for (int layer = 0; layer < 3; ++layer) {
        k_qkvs<<<gemm_grid, 256, 0, stream>>>(h, Wt, bq, bk, bv, bs, qkvs);
        float* hout = (layer == 2) ? out : h;
        k_conv<<<(NN + 3) / 4, 256, 0, stream>>>(row_ptr, erec, We, qkvs, hout);
    }
}